// Round 3
// baseline (2830.763 us; speedup 1.0000x reference)
//
#include <hip/hip_runtime.h>
#include <stdint.h>

// FFJORD block: B=2048, D=512, H=1024, 9 RK38 steps x 4 stages, 2 Hutchinson probes.
// f32 in/out. bf16 MFMA GEMMs, f32 accumulate, fp32 RK state.
// PRNG: JAX threefry partitionable (verified R7).
// R17: FULL FUSION. Evidence R14-R16: wall time flat (1394-1405) across three
// radically different f1 memory systems => binder is the 87-dispatch dependent
// chain (drain+launch gap + per-boundary L2 invalidation), not kernel inner
// loops. Fix: one persistent kernel, 256 blocks (=CUs, 1/CU forced by 86KB
// LDS), manual agent-scope grid barrier (monotonic counter, s_sleep poll).
// egen folded into f3 phase of stage 4k-1 (ring provably dead there); k_out
// folded as final phase; f3 upgraded to 64x64 tiles + 3-ring counted vmcnt.
// All cross-phase traffic intra-XCD by bm-affinity (zin/hbuf/div/lp).

#define B_N 2048
#define D_N 512
#define H_N 1024
#define BD (B_N * D_N)

typedef unsigned short u16;
typedef __attribute__((ext_vector_type(8))) short s16x8;   // 8 x bf16
typedef __attribute__((ext_vector_type(4))) float f32x4;   // MFMA accumulator

typedef __attribute__((address_space(1))) const uint32_t ga_u32;
typedef __attribute__((address_space(3))) uint32_t ls_u32;

#if __has_builtin(__builtin_amdgcn_alignbit)
#define ROTL32(x, r) __builtin_amdgcn_alignbit((x), (x), 32 - (r))
#else
#define ROTL32(x, r) (((x) << (r)) | ((x) >> (32 - (r))))
#endif

__device__ __forceinline__ u16 f2bf(float f) {
  union { float f; uint32_t u; } c; c.f = f;
  uint32_t r = c.u + 0x7FFFu + ((c.u >> 16) & 1u);  // RTNE
  return (u16)(r >> 16);
}
__device__ __forceinline__ float fast_tanh(float v) {
  float e = __expf(2.0f * fabsf(v));
  float t = 1.0f - 2.0f / (e + 1.0f);
  return copysignf(t, v);
}

struct U2 { uint32_t x, y; };

// Threefry-2x32, 20 rounds — KAT-verified.
__device__ __forceinline__ U2 tf2x32(uint32_t k0, uint32_t k1, uint32_t x0, uint32_t x1) {
  uint32_t k2 = k0 ^ k1 ^ 0x1BD11BDAu;
#define RND(r) { x0 += x1; x1 = ROTL32(x1, r); x1 ^= x0; }
  x0 += k0; x1 += k1;
  RND(13) RND(15) RND(26) RND(6)
  x0 += k1; x1 += k2 + 1u;
  RND(17) RND(29) RND(16) RND(24)
  x0 += k2; x1 += k0 + 2u;
  RND(13) RND(15) RND(26) RND(6)
  x0 += k0; x1 += k1 + 3u;
  RND(17) RND(29) RND(16) RND(24)
  x0 += k1; x1 += k2 + 4u;
  RND(13) RND(15) RND(26) RND(6)
  x0 += k2; x1 += k0 + 5u;
#undef RND
  U2 r; r.x = x0; r.y = x1; return r;
}

// Partitionable key schedule (verified R7).
__global__ void k_keysched(uint32_t* __restrict__ ekeys) {
  if (threadIdx.x != 0 || blockIdx.x != 0) return;
  uint32_t kx = 0u, ky = 1234u;
  for (int s = 0; s < 9; ++s) {
    for (int st = 0; st < 4; ++st) {
      U2 kst = tf2x32(kx, ky, 0u, (uint32_t)(st + 1));
      for (int pr = 0; pr < 2; ++pr) {
        U2 fo = tf2x32(kst.x, kst.y, 0u, (uint32_t)pr);
        U2 k2 = tf2x32(fo.x, fo.y, 0u, 1u);
        ekeys[(s * 4 + st) * 4 + pr * 2 + 0] = k2.x;
        ekeys[(s * 4 + st) * 4 + pr * 2 + 1] = k2.y;
      }
    }
    U2 c = tf2x32(kx, ky, 0u, 0u);
    kx = c.x; ky = c.y;
  }
}

__global__ void k_init(const float* __restrict__ x, float* __restrict__ z, u16* __restrict__ zin,
                       float* __restrict__ lp, float* __restrict__ d0, float* __restrict__ d1,
                       uint32_t* __restrict__ bar) {
  int i = blockIdx.x * 256 + threadIdx.x;
  if (i < BD) { float v = x[i]; z[i] = v; zin[i] = f2bf(v); }
  if (i < B_N) { lp[i] = 0.f; d0[i] = 0.f; d1[i] = 0.f; }
  if (i == 0) *bar = 0u;
}

__global__ void k_cvtT(const float* __restrict__ src, u16* __restrict__ dst, int R, int C) {
  int i = blockIdx.x * 256 + threadIdx.x;
  if (i >= R * C) return;
  int c = i / R, r = i - c * R;
  dst[i] = f2bf(src[(size_t)r * C + c]);
}
__global__ void k_cvt(const float* __restrict__ src, u16* __restrict__ dst, int n) {
  int i = blockIdx.x * 256 + threadIdx.x;
  if (i < n) dst[i] = f2bf(src[i]);
}

__global__ void k_sentinel(float* __restrict__ out, int n) {
  int i = blockIdx.x * 256 + threadIdx.x;
  if (i < n) out[i] = 12345.0f;
}

// Device-scope grid barrier. Safe: 86KB LDS => 1 block/CU, grid 256 = #CUs,
// blocks never exit before final phase => all co-resident; monotonic counter
// (re-zeroed by k_init each graph replay).
__device__ __forceinline__ void gridbar(uint32_t* bar, uint32_t tgt) {
  __syncthreads();                       // compiler drains vmcnt/lgkm before s_barrier
  if (threadIdx.x == 0) {
    __threadfence();                     // release: agent-scope WB
    __hip_atomic_fetch_add(bar, 1u, __ATOMIC_RELAXED, __HIP_MEMORY_SCOPE_AGENT);
    while (__hip_atomic_load(bar, __ATOMIC_RELAXED, __HIP_MEMORY_SCOPE_AGENT) < tgt)
      __builtin_amdgcn_s_sleep(2);
    __threadfence();                     // acquire: invalidate stale L1/L2
  }
  __syncthreads();
}

// LDS chunk swizzle (R13-verified): chunk c of 16-row-group row r at chunk c^((r>>1)&3).
// f1: 64x128 block tile, 4 waves of 32x64, K=512, 16 K-steps, 3-ring vmcnt(7).
// f3: 64x64 block tile, 4 waves of 32x32, K=1024, 32 K-steps, 3-ring vmcnt(2).
__global__ __launch_bounds__(256, 1)
void k_fused(const uint32_t* __restrict__ keys, u16* __restrict__ ebf,
             u16* __restrict__ zin,
             const u16* __restrict__ W1T, const u16* __restrict__ W2b, const u16* __restrict__ W2T,
             const float* __restrict__ b1v, const float* __restrict__ tw1v, const float* __restrict__ b2v,
             float* __restrict__ z, float* __restrict__ ACC, float* __restrict__ T,
             u16* __restrict__ hbuf,
             float* __restrict__ lp, float* __restrict__ div0, float* __restrict__ div1,
             uint32_t* __restrict__ bar, float* __restrict__ outp) {
  __shared__ u16 S[3][14336];   // 86KB: f1 ring [zin|e0|e1|W1|W2]x3; f3 ring aliased at base
  const int tid = threadIdx.x, wave = tid >> 6, lane = tid & 63;
  const int xcd = blockIdx.x & 7, idx = blockIdx.x >> 3;   // 256 blocks: 32/XCD
  const int bm = xcd * 4 + (idx >> 3);       // row-slab of 64, pinned to XCD
  const int bh = idx & 7;                    // f1: col-block of 128; f3: col-block of 64
  const int row0 = bm * 64;
  const int wm = wave >> 1, wn = wave & 1, r16 = lane & 15, q = lane >> 4;
  const int srow = lane >> 2;
  const int scol = (((lane & 3) ^ ((srow >> 1) & 3))) * 8;   // swizzled source chunk
  const int cqa = (q ^ ((r16 >> 1) & 3)) * 8;                // swizzled read chunk

  uint32_t tgt = 0;

  // ---- egen: generate e ring for stages gs..gs+3 (this block's XCD share) ----
  auto egen_grp = [&](int gs) {
#pragma unroll
    for (int rep = 0; rep < 4; ++rep) {
      const int uu = (idx * 256 + tid) * 4 + rep;            // 0..32767 per XCD
      const int slab = xcd * 4 + (uu >> 13);
      const int r13 = uu & 8191;
      const int stg = gs + (r13 >> 11);
      const int r11 = r13 & 2047;
      const int probe = r11 >> 10;
      const int unit = r11 & 1023;
      const uint32_t p0 = (uint32_t)(slab * 32768 + unit * 32);
      uint32_t k0 = keys[stg * 4 + probe * 2], k1 = keys[stg * 4 + probe * 2 + 1];
      uint4* dst = (uint4*)(ebf + (size_t)(stg & 3) * (2 * (size_t)BD) + (size_t)probe * BD + (size_t)p0);
#pragma unroll
      for (int g = 0; g < 4; ++g) {
        uint32_t pr[4];
#pragma unroll
        for (int h = 0; h < 4; ++h) {
          uint32_t c0 = p0 + g * 8 + h * 2;
          U2 r0 = tf2x32(k0, k1, 0u, c0);
          U2 r1 = tf2x32(k0, k1, 0u, c0 + 1u);
          pr[h] = (((r0.x ^ r0.y) & 1u) ? 0x3F80u : 0xBF80u) |
                  (((r1.x ^ r1.y) & 1u) ? 0x3F800000u : 0xBF800000u);
        }
        uint4 v; v.x = pr[0]; v.y = pr[1]; v.z = pr[2]; v.w = pr[3];
        dst[g] = v;
      }
    }
  };

  egen_grp(0);
  tgt += 256; gridbar(bar, tgt);

  for (int st = 0; st < 36; ++st) {
    const int s9 = st >> 2, rsub = st & 3;
    const float t0f = (float)s9 / 9.0f;
    const float t1f = (float)(s9 + 1) / 9.0f;
    const float dtt = t1f - t0f;
    const float tstage = (rsub == 0) ? t0f : (rsub == 1) ? (t0f + dtt / 3.0f)
                       : (rsub == 2) ? (t0f + dtt * 2.0f / 3.0f) : t1f;
    const float wdt = dtt * 0.125f * ((rsub == 1 || rsub == 2) ? 3.0f : 1.0f);

    // ================= f1 phase =================
    {
      const u16* e0g = ebf + (size_t)(st & 3) * (2 * (size_t)BD);
      const u16* e1g = e0g + BD;
      const int col0 = bh * 128;

      f32x4 az[2][4], au0[2][4], au1[2][4], av0[2][4], av1[2][4];
#pragma unroll
      for (int i = 0; i < 2; ++i)
#pragma unroll
        for (int j = 0; j < 4; ++j) {
          az[i][j] = (f32x4){0,0,0,0}; au0[i][j] = (f32x4){0,0,0,0}; au1[i][j] = (f32x4){0,0,0,0};
          av0[i][j] = (f32x4){0,0,0,0}; av1[i][j] = (f32x4){0,0,0,0};
        }

      // slot s = li*4+wave: s<12 -> A {zin,e0,e1} part s&3; s>=12 -> B {W1T,W2b} part (s-12)&7
      const u16* gp[7];
#pragma unroll
      for (int li = 0; li < 7; ++li) {
        const int s = li * 4 + wave;
        const u16* base;
        int row;
        if (s < 12) {
          const int mat = s >> 2;
          base = (mat == 0) ? zin : (mat == 1) ? e0g : e1g;
          row = row0 + (s & 3) * 16 + srow;
        } else {
          const int t = s - 12;
          base = (t < 8) ? W1T : W2b;
          row = col0 + (t & 7) * 16 + srow;
        }
        gp[li] = base + (size_t)row * 512 + scol;
      }

      auto stg1 = [&](int kt, int slot) {
        u16* b = &S[slot][0];
#pragma unroll
        for (int li = 0; li < 7; ++li)
          __builtin_amdgcn_global_load_lds((ga_u32*)(gp[li] + kt),
                                           (ls_u32*)(b + (li * 4 + wave) * 512), 16, 0, 0);
      };
      auto cmp1 = [&](int slot) {
        const u16* b = &S[slot][0];
        s16x8 zf[2], e0f[2], e1f[2], w1f[4], w2f[4];
#pragma unroll
        for (int i = 0; i < 2; ++i) {
          const int ao = (wm * 32 + i * 16 + r16) * 32 + cqa;
          zf[i]  = *(const s16x8*)(b + 0    + ao);
          e0f[i] = *(const s16x8*)(b + 2048 + ao);
          e1f[i] = *(const s16x8*)(b + 4096 + ao);
        }
#pragma unroll
        for (int j = 0; j < 4; ++j) {
          const int bo = (wn * 64 + j * 16 + r16) * 32 + cqa;
          w1f[j] = *(const s16x8*)(b + 6144  + bo);
          w2f[j] = *(const s16x8*)(b + 10240 + bo);
        }
#pragma unroll
        for (int i = 0; i < 2; ++i)
#pragma unroll
          for (int j = 0; j < 4; ++j) {
            az[i][j]  = __builtin_amdgcn_mfma_f32_16x16x32_bf16(zf[i],  w1f[j], az[i][j],  0, 0, 0);
            au0[i][j] = __builtin_amdgcn_mfma_f32_16x16x32_bf16(e0f[i], w1f[j], au0[i][j], 0, 0, 0);
            au1[i][j] = __builtin_amdgcn_mfma_f32_16x16x32_bf16(e1f[i], w1f[j], au1[i][j], 0, 0, 0);
            av0[i][j] = __builtin_amdgcn_mfma_f32_16x16x32_bf16(e0f[i], w2f[j], av0[i][j], 0, 0, 0);
            av1[i][j] = __builtin_amdgcn_mfma_f32_16x16x32_bf16(e1f[i], w2f[j], av1[i][j], 0, 0, 0);
          }
      };

      stg1(0, 0);
      stg1(32, 1);
      int cur = 0, nxt = 2;
      for (int it = 0; it < 15; ++it) {
        asm volatile("s_waitcnt vmcnt(7)" ::: "memory");
        __builtin_amdgcn_s_barrier();
        asm volatile("" ::: "memory");
        if (it + 2 < 16) stg1((it + 2) * 32, nxt);
        cmp1(cur);
        if (++cur == 3) cur = 0;
        if (++nxt == 3) nxt = 0;
      }
      asm volatile("s_waitcnt vmcnt(0)" ::: "memory");
      __builtin_amdgcn_s_barrier();
      asm volatile("" ::: "memory");
      cmp1(cur);

      float d0s[2][4], d1s[2][4];
#pragma unroll
      for (int i = 0; i < 2; ++i)
#pragma unroll
        for (int rr = 0; rr < 4; ++rr) { d0s[i][rr] = 0.f; d1s[i][rr] = 0.f; }

#pragma unroll
      for (int j = 0; j < 4; ++j) {
        const int gcol = col0 + wn * 64 + j * 16 + r16;
        const float colb = b1v[gcol] + tstage * tw1v[gcol];
#pragma unroll
        for (int i = 0; i < 2; ++i) {
          const int rbase = row0 + wm * 32 + i * 16 + q * 4;   // C/D: row=quad*4+reg
#pragma unroll
          for (int rr = 0; rr < 4; ++rr) {
            float hv = fast_tanh(az[i][j][rr] + colb);
            hbuf[(size_t)(rbase + rr) * H_N + gcol] = f2bf(hv);
            float sd = 1.f - hv * hv;
            d0s[i][rr] += sd * au0[i][j][rr] * av0[i][j][rr];
            d1s[i][rr] += sd * au1[i][j][rr] * av1[i][j][rr];
          }
        }
      }
#pragma unroll
      for (int i = 0; i < 2; ++i)
#pragma unroll
        for (int rr = 0; rr < 4; ++rr) {
          float a = d0s[i][rr], bb = d1s[i][rr];
#pragma unroll
          for (int m = 1; m < 16; m <<= 1) { a += __shfl_xor(a, m); bb += __shfl_xor(bb, m); }
          if (r16 == 0) {
            int grow = row0 + wm * 32 + i * 16 + q * 4 + rr;
            atomicAdd(&div0[grow], a);
            atomicAdd(&div1[grow], bb);
          }
        }
    }
    tgt += 256; gridbar(bar, tgt);

    // ================= f3 phase (+ lp/div apply, + egen for next group) =================
    {
      const int col0 = bh * 64;
      u16* S3 = &S[0][0];                  // 3 ring slots of 4096 u16 (A 2048 | B 2048)

      f32x4 a3[2][2];
      a3[0][0] = (f32x4){0,0,0,0}; a3[0][1] = (f32x4){0,0,0,0};
      a3[1][0] = (f32x4){0,0,0,0}; a3[1][1] = (f32x4){0,0,0,0};

      // li=0 -> A slot=wave (hbuf rows); li=1 -> B slot=wave (W2T rows)
      const u16* gp3[2];
      gp3[0] = hbuf + (size_t)(row0 + wave * 16 + srow) * 1024 + scol;
      gp3[1] = W2T  + (size_t)(col0 + wave * 16 + srow) * 1024 + scol;

      auto stg3 = [&](int kt, int slot) {
        u16* b = S3 + slot * 4096;
        __builtin_amdgcn_global_load_lds((ga_u32*)(gp3[0] + kt),
                                         (ls_u32*)(b + wave * 512), 16, 0, 0);
        __builtin_amdgcn_global_load_lds((ga_u32*)(gp3[1] + kt),
                                         (ls_u32*)(b + 2048 + wave * 512), 16, 0, 0);
      };
      auto cmp3 = [&](int slot) {
        const u16* b = S3 + slot * 4096;
        s16x8 af[2], bf[2];
#pragma unroll
        for (int i = 0; i < 2; ++i)
          af[i] = *(const s16x8*)(b + (wm * 32 + i * 16 + r16) * 32 + cqa);
#pragma unroll
        for (int j = 0; j < 2; ++j)
          bf[j] = *(const s16x8*)(b + 2048 + (wn * 32 + j * 16 + r16) * 32 + cqa);
#pragma unroll
        for (int i = 0; i < 2; ++i)
#pragma unroll
          for (int j = 0; j < 2; ++j)
            a3[i][j] = __builtin_amdgcn_mfma_f32_16x16x32_bf16(af[i], bf[j], a3[i][j], 0, 0, 0);
      };

      stg3(0, 0);
      stg3(32, 1);

      if (bh == 0 && tid < 64) {           // apply clipped div to lp; reset accumulators
        int b = row0 + tid;
        float c = 0.5f * (div0[b] + div1[b]);
        c = fminf(fmaxf(c, -100.f), 100.f);
        lp[b] -= wdt * c;
        div0[b] = 0.f; div1[b] = 0.f;
      }

      int cur = 0, nxt = 2;
      for (int it = 0; it < 31; ++it) {
        asm volatile("s_waitcnt vmcnt(2)" ::: "memory");
        __builtin_amdgcn_s_barrier();
        asm volatile("" ::: "memory");
        if (it + 2 < 32) stg3((it + 2) * 32, nxt);
        cmp3(cur);
        if (++cur == 3) cur = 0;
        if (++nxt == 3) nxt = 0;
      }
      asm volatile("s_waitcnt vmcnt(0)" ::: "memory");
      __builtin_amdgcn_s_barrier();
      asm volatile("" ::: "memory");
      cmp3(cur);

      // RK38 epilogue
#pragma unroll
      for (int j = 0; j < 2; ++j) {
        const int gcol = col0 + wn * 32 + j * 16 + r16;
        const float cb = b2v[gcol];
#pragma unroll
        for (int i = 0; i < 2; ++i) {
          const int rbase = row0 + wm * 32 + i * 16 + q * 4;
#pragma unroll
          for (int rr = 0; rr < 4; ++rr) {
            const size_t idx2 = (size_t)(rbase + rr) * D_N + gcol;
            const float f = a3[i][j][rr] + cb;
            if (rsub == 0) {
              ACC[idx2] = dtt * 0.125f * f;
              T[idx2]   = dtt * f;
              zin[idx2] = f2bf(z[idx2] + dtt * f * (1.f / 3.f));
            } else if (rsub == 1) {
              float t_ = T[idx2];
              ACC[idx2] += 0.375f * dtt * f;
              zin[idx2] = f2bf(z[idx2] + dtt * f - t_ * (1.f / 3.f));
              T[idx2]   = t_ - dtt * f;
            } else if (rsub == 2) {
              ACC[idx2] += 0.375f * dtt * f;
              zin[idx2] = f2bf(z[idx2] + T[idx2] + dtt * f);
            } else {
              float zn = z[idx2] + ACC[idx2] + dtt * 0.125f * f;
              z[idx2]   = zn;
              zin[idx2] = f2bf(zn);
            }
          }
        }
      }

      // regen e ring for next 4 stages: all slots dead here (f1(st) consumed last)
      if ((st & 3) == 3 && st + 1 < 36) egen_grp(st + 1);
    }
    tgt += 256; gridbar(bar, tgt);
  }

  // ================= out phase: rep + logprob =================
#pragma unroll
  for (int rr = 0; rr < 2; ++rr) {
    const int b = bm * 64 + bh * 8 + wave * 2 + rr;
    const float* zr = z + (size_t)b * D_N + lane * 8;
    float4 v0 = *(const float4*)zr;
    float4 v1 = *(const float4*)(zr + 4);
    *(float4*)(outp + (size_t)b * D_N + lane * 8)     = v0;
    *(float4*)(outp + (size_t)b * D_N + lane * 8 + 4) = v1;
    float ss = v0.x*v0.x + v0.y*v0.y + v0.z*v0.z + v0.w*v0.w
             + v1.x*v1.x + v1.y*v1.y + v1.z*v1.z + v1.w*v1.w;
#pragma unroll
    for (int m = 1; m < 64; m <<= 1) ss += __shfl_xor(ss, m);
    if (lane == 0) outp[(size_t)BD + b] = -0.5f * ss + lp[b];
  }
}

extern "C" void kernel_launch(void* const* d_in, const int* in_sizes, int n_in,
                              void* d_out, int out_size, void* d_ws, size_t ws_size,
                              hipStream_t stream) {
  const float* x   = (const float*)d_in[0];
  const float* W1  = (const float*)d_in[1];
  const float* b1  = (const float*)d_in[2];
  const float* tw1 = (const float*)d_in[3];
  const float* W2  = (const float*)d_in[4];
  const float* b2  = (const float*)d_in[5];
  float* outp = (float*)d_out;

  const size_t NEEDED = (size_t)45 << 20;
  if (ws_size < NEEDED) {
    k_sentinel<<<(BD + B_N + 255) / 256, 256, 0, stream>>>(outp, BD + B_N);
    return;
  }
  char* w = (char*)d_ws;
  auto carve = [&](size_t bytes) { char* p = w; w += (bytes + 255) & ~(size_t)255; return p; };
  uint32_t* keys = (uint32_t*)carve(144 * sizeof(uint32_t));
  u16* ebf   = (u16*)carve((size_t)4 * 2 * BD * 2);               // 16 MB: 4-slot e ring
  float* z   = (float*)carve((size_t)BD * 4);
  float* ACC = (float*)carve((size_t)BD * 4);
  float* T   = (float*)carve((size_t)BD * 4);
  u16* zin   = (u16*)carve((size_t)BD * 2);
  u16* hbuf  = (u16*)carve((size_t)B_N * H_N * 2);
  u16* W1T   = (u16*)carve((size_t)H_N * D_N * 2);
  u16* W2b   = (u16*)carve((size_t)H_N * D_N * 2);
  u16* W2T   = (u16*)carve((size_t)D_N * H_N * 2);
  float* lp   = (float*)carve((size_t)B_N * 4);
  float* div0 = (float*)carve((size_t)B_N * 4);
  float* div1 = (float*)carve((size_t)B_N * 4);
  uint32_t* bar = (uint32_t*)carve(256);

  k_keysched<<<1, 1, 0, stream>>>(keys);
  k_init<<<BD / 256, 256, 0, stream>>>(x, z, zin, lp, div0, div1, bar);
  k_cvtT<<<(D_N * H_N) / 256, 256, 0, stream>>>(W1, W1T, D_N, H_N);
  k_cvt <<<(H_N * D_N) / 256, 256, 0, stream>>>(W2, W2b, H_N * D_N);
  k_cvtT<<<(H_N * D_N) / 256, 256, 0, stream>>>(W2, W2T, H_N, D_N);

  k_fused<<<256, 256, 0, stream>>>(keys, ebf, zin, W1T, W2b, W2T, b1, tw1, b2,
                                   z, ACC, T, hbuf, lp, div0, div1, bar, outp);
}

// Round 4
// 1874.332 us; speedup vs baseline: 1.5103x; 1.5103x over previous
//
#include <hip/hip_runtime.h>
#include <stdint.h>

// FFJORD block: B=2048, D=512, H=1024, 9 RK38 steps x 4 stages, 2 Hutchinson probes.
// f32 in/out. bf16 MFMA GEMMs, f32 accumulate, fp32 RK state.
// PRNG: JAX threefry partitionable (verified R7).
// R18: slab-local sync. R17 attribution: fused 2806us, MfmaUtil 6.8%, 80%
// stalled; extra 40us/stage = 2 x 256-way contended gridbar (~20us each) +
// egen burst imbalance. ALL cross-block deps are slab-local (8 blocks, same
// XCD: zin/hbuf/div/lp/e). Fix: (1) 32 independent 8-way slab barriers
// (padded counters, monotonic); (2) egen balanced: each f3 phase regens
// stage st+4's e (slot just freed), 1 unit/thread; (3) rings deepened to
// 4-slot/3-ahead (f1 vmcnt(14), f3 vmcnt(4)) to cover ~1.3us LLC latency;
// LDS 112KB, still 1 block/CU. Release=RELEASE fetch_add (wbl2: div reset ->
// LLC before next f1 atomics); acquire=fence(ACQUIRE,agent) in thread0.

#define B_N 2048
#define D_N 512
#define H_N 1024
#define BD (B_N * D_N)

typedef unsigned short u16;
typedef __attribute__((ext_vector_type(8))) short s16x8;   // 8 x bf16
typedef __attribute__((ext_vector_type(4))) float f32x4;   // MFMA accumulator

typedef __attribute__((address_space(1))) const uint32_t ga_u32;
typedef __attribute__((address_space(3))) uint32_t ls_u32;

#if __has_builtin(__builtin_amdgcn_alignbit)
#define ROTL32(x, r) __builtin_amdgcn_alignbit((x), (x), 32 - (r))
#else
#define ROTL32(x, r) (((x) << (r)) | ((x) >> (32 - (r))))
#endif

__device__ __forceinline__ u16 f2bf(float f) {
  union { float f; uint32_t u; } c; c.f = f;
  uint32_t r = c.u + 0x7FFFu + ((c.u >> 16) & 1u);  // RTNE
  return (u16)(r >> 16);
}
__device__ __forceinline__ float fast_tanh(float v) {
  float e = __expf(2.0f * fabsf(v));
  float t = 1.0f - 2.0f / (e + 1.0f);
  return copysignf(t, v);
}

struct U2 { uint32_t x, y; };

// Threefry-2x32, 20 rounds — KAT-verified.
__device__ __forceinline__ U2 tf2x32(uint32_t k0, uint32_t k1, uint32_t x0, uint32_t x1) {
  uint32_t k2 = k0 ^ k1 ^ 0x1BD11BDAu;
#define RND(r) { x0 += x1; x1 = ROTL32(x1, r); x1 ^= x0; }
  x0 += k0; x1 += k1;
  RND(13) RND(15) RND(26) RND(6)
  x0 += k1; x1 += k2 + 1u;
  RND(17) RND(29) RND(16) RND(24)
  x0 += k2; x1 += k0 + 2u;
  RND(13) RND(15) RND(26) RND(6)
  x0 += k0; x1 += k1 + 3u;
  RND(17) RND(29) RND(16) RND(24)
  x0 += k1; x1 += k2 + 4u;
  RND(13) RND(15) RND(26) RND(6)
  x0 += k2; x1 += k0 + 5u;
#undef RND
  U2 r; r.x = x0; r.y = x1; return r;
}

// Partitionable key schedule (verified R7).
__global__ void k_keysched(uint32_t* __restrict__ ekeys) {
  if (threadIdx.x != 0 || blockIdx.x != 0) return;
  uint32_t kx = 0u, ky = 1234u;
  for (int s = 0; s < 9; ++s) {
    for (int st = 0; st < 4; ++st) {
      U2 kst = tf2x32(kx, ky, 0u, (uint32_t)(st + 1));
      for (int pr = 0; pr < 2; ++pr) {
        U2 fo = tf2x32(kst.x, kst.y, 0u, (uint32_t)pr);
        U2 k2 = tf2x32(fo.x, fo.y, 0u, 1u);
        ekeys[(s * 4 + st) * 4 + pr * 2 + 0] = k2.x;
        ekeys[(s * 4 + st) * 4 + pr * 2 + 1] = k2.y;
      }
    }
    U2 c = tf2x32(kx, ky, 0u, 0u);
    kx = c.x; ky = c.y;
  }
}

__global__ void k_init(const float* __restrict__ x, float* __restrict__ z, u16* __restrict__ zin,
                       float* __restrict__ lp, float* __restrict__ d0, float* __restrict__ d1,
                       uint32_t* __restrict__ barv) {
  int i = blockIdx.x * 256 + threadIdx.x;
  if (i < BD) { float v = x[i]; z[i] = v; zin[i] = f2bf(v); }
  if (i < B_N) { lp[i] = 0.f; d0[i] = 0.f; d1[i] = 0.f; }
  if (i < 1024) barv[i] = 0u;                    // 32 slab counters, 128B stride
}

__global__ void k_cvtT(const float* __restrict__ src, u16* __restrict__ dst, int R, int C) {
  int i = blockIdx.x * 256 + threadIdx.x;
  if (i >= R * C) return;
  int c = i / R, r = i - c * R;
  dst[i] = f2bf(src[(size_t)r * C + c]);
}
__global__ void k_cvt(const float* __restrict__ src, u16* __restrict__ dst, int n) {
  int i = blockIdx.x * 256 + threadIdx.x;
  if (i < n) dst[i] = f2bf(src[i]);
}

__global__ void k_sentinel(float* __restrict__ out, int n) {
  int i = blockIdx.x * 256 + threadIdx.x;
  if (i < n) out[i] = 12345.0f;
}

// 8-way slab barrier (monotonic counter, re-zeroed by k_init each replay).
// All 8 participants are on the SAME XCD; data flows via shared XCD L2.
// Release: RELEASE RMW (waitcnt + wbl2 -> dirty slab data reaches LLC/L2).
// Acquire: fence(ACQUIRE, agent) in thread0 (inv L1/L2 -> fresh div/e/zin).
__device__ __forceinline__ void slab_bar(uint32_t* ctr, uint32_t tgt) {
  __syncthreads();
  if (threadIdx.x == 0) {
    __hip_atomic_fetch_add(ctr, 1u, __ATOMIC_RELEASE, __HIP_MEMORY_SCOPE_AGENT);
    while (__hip_atomic_load(ctr, __ATOMIC_RELAXED, __HIP_MEMORY_SCOPE_AGENT) < tgt)
      __builtin_amdgcn_s_sleep(1);
    __builtin_amdgcn_fence(__ATOMIC_ACQUIRE, "agent");
  }
  __syncthreads();
}

// LDS chunk swizzle (R13-verified): chunk c of 16-row-group row r at chunk c^((r>>1)&3).
// f1: 64x128 block tile, 4 waves of 32x64, K=512, 16 K-steps, 4-ring vmcnt(14).
// f3: 64x64 block tile, 4 waves of 32x32, K=1024, 32 K-steps, 4-ring vmcnt(4).
__global__ __launch_bounds__(256, 1)
void k_fused(const uint32_t* __restrict__ keys, u16* __restrict__ ebf,
             u16* __restrict__ zin,
             const u16* __restrict__ W1T, const u16* __restrict__ W2b, const u16* __restrict__ W2T,
             const float* __restrict__ b1v, const float* __restrict__ tw1v, const float* __restrict__ b2v,
             float* __restrict__ z, float* __restrict__ ACC, float* __restrict__ T,
             u16* __restrict__ hbuf,
             float* __restrict__ lp, float* __restrict__ div0, float* __restrict__ div1,
             uint32_t* __restrict__ barv, float* __restrict__ outp) {
  __shared__ u16 S[4][14336];   // 112KB: f1 ring [zin|e0|e1|W1|W2]x4; f3 ring aliased at base
  const int tid = threadIdx.x, wave = tid >> 6, lane = tid & 63;
  const int xcd = blockIdx.x & 7, idx = blockIdx.x >> 3;   // 256 blocks: 32/XCD
  const int bm = xcd * 4 + (idx >> 3);       // row-slab of 64, pinned to XCD
  const int bh = idx & 7;                    // f1: col-block of 128; f3: col-block of 64
  const int row0 = bm * 64;
  const int wm = wave >> 1, wn = wave & 1, r16 = lane & 15, q = lane >> 4;
  const int srow = lane >> 2;
  const int scol = (((lane & 3) ^ ((srow >> 1) & 3))) * 8;   // swizzled source chunk
  const int cqa = (q ^ ((r16 >> 1) & 3)) * 8;                // swizzled read chunk

  uint32_t* ctr = barv + bm * 32;            // this slab's barrier counter
  uint32_t tgt = 0;

  // ---- egen: one (stage, unit) task per call; slab-local ----
  auto egen_unit = [&](int stg, int u) {
    const int probe = u >> 10, unit = u & 1023;
    const uint32_t p0 = (uint32_t)(bm * 32768 + unit * 32);
    uint32_t k0 = keys[stg * 4 + probe * 2], k1 = keys[stg * 4 + probe * 2 + 1];
    uint4* dst = (uint4*)(ebf + (size_t)(stg & 3) * (2 * (size_t)BD) + (size_t)probe * BD + (size_t)p0);
#pragma unroll
    for (int g = 0; g < 4; ++g) {
      uint32_t pr[4];
#pragma unroll
      for (int h = 0; h < 4; ++h) {
        uint32_t c0 = p0 + g * 8 + h * 2;
        U2 r0 = tf2x32(k0, k1, 0u, c0);
        U2 r1 = tf2x32(k0, k1, 0u, c0 + 1u);
        pr[h] = (((r0.x ^ r0.y) & 1u) ? 0x3F80u : 0xBF80u) |
                (((r1.x ^ r1.y) & 1u) ? 0x3F800000u : 0xBF800000u);
      }
      uint4 v; v.x = pr[0]; v.y = pr[1]; v.z = pr[2]; v.w = pr[3];
      dst[g] = v;
    }
  };

  // Prologue: e for stages 0..3 of this slab (2048 threads x 4 tasks).
#pragma unroll
  for (int r = 0; r < 4; ++r) egen_unit(r, bh * 256 + tid);
  tgt += 8; slab_bar(ctr, tgt);

  for (int st = 0; st < 36; ++st) {
    const int s9 = st >> 2, rsub = st & 3;
    const float t0f = (float)s9 / 9.0f;
    const float t1f = (float)(s9 + 1) / 9.0f;
    const float dtt = t1f - t0f;
    const float tstage = (rsub == 0) ? t0f : (rsub == 1) ? (t0f + dtt / 3.0f)
                       : (rsub == 2) ? (t0f + dtt * 2.0f / 3.0f) : t1f;
    const float wdt = dtt * 0.125f * ((rsub == 1 || rsub == 2) ? 3.0f : 1.0f);

    // ================= f1 phase =================
    {
      const u16* e0g = ebf + (size_t)(st & 3) * (2 * (size_t)BD);
      const u16* e1g = e0g + BD;
      const int col0 = bh * 128;

      f32x4 az[2][4], au0[2][4], au1[2][4], av0[2][4], av1[2][4];
#pragma unroll
      for (int i = 0; i < 2; ++i)
#pragma unroll
        for (int j = 0; j < 4; ++j) {
          az[i][j] = (f32x4){0,0,0,0}; au0[i][j] = (f32x4){0,0,0,0}; au1[i][j] = (f32x4){0,0,0,0};
          av0[i][j] = (f32x4){0,0,0,0}; av1[i][j] = (f32x4){0,0,0,0};
        }

      // slot s = li*4+wave: s<12 -> A {zin,e0,e1} part s&3; s>=12 -> B {W1T,W2b} part (s-12)&7
      const u16* gp[7];
#pragma unroll
      for (int li = 0; li < 7; ++li) {
        const int s = li * 4 + wave;
        const u16* base;
        int row;
        if (s < 12) {
          const int mat = s >> 2;
          base = (mat == 0) ? zin : (mat == 1) ? e0g : e1g;
          row = row0 + (s & 3) * 16 + srow;
        } else {
          const int t = s - 12;
          base = (t < 8) ? W1T : W2b;
          row = col0 + (t & 7) * 16 + srow;
        }
        gp[li] = base + (size_t)row * 512 + scol;
      }

      auto stg1 = [&](int kt, int slot) {
        u16* b = &S[slot][0];
#pragma unroll
        for (int li = 0; li < 7; ++li)
          __builtin_amdgcn_global_load_lds((ga_u32*)(gp[li] + kt),
                                           (ls_u32*)(b + (li * 4 + wave) * 512), 16, 0, 0);
      };
      auto cmp1 = [&](int slot) {
        const u16* b = &S[slot][0];
        s16x8 zf[2], e0f[2], e1f[2], w1f[4], w2f[4];
#pragma unroll
        for (int i = 0; i < 2; ++i) {
          const int ao = (wm * 32 + i * 16 + r16) * 32 + cqa;
          zf[i]  = *(const s16x8*)(b + 0    + ao);
          e0f[i] = *(const s16x8*)(b + 2048 + ao);
          e1f[i] = *(const s16x8*)(b + 4096 + ao);
        }
#pragma unroll
        for (int j = 0; j < 4; ++j) {
          const int bo = (wn * 64 + j * 16 + r16) * 32 + cqa;
          w1f[j] = *(const s16x8*)(b + 6144  + bo);
          w2f[j] = *(const s16x8*)(b + 10240 + bo);
        }
#pragma unroll
        for (int i = 0; i < 2; ++i)
#pragma unroll
          for (int j = 0; j < 4; ++j) {
            az[i][j]  = __builtin_amdgcn_mfma_f32_16x16x32_bf16(zf[i],  w1f[j], az[i][j],  0, 0, 0);
            au0[i][j] = __builtin_amdgcn_mfma_f32_16x16x32_bf16(e0f[i], w1f[j], au0[i][j], 0, 0, 0);
            au1[i][j] = __builtin_amdgcn_mfma_f32_16x16x32_bf16(e1f[i], w1f[j], au1[i][j], 0, 0, 0);
            av0[i][j] = __builtin_amdgcn_mfma_f32_16x16x32_bf16(e0f[i], w2f[j], av0[i][j], 0, 0, 0);
            av1[i][j] = __builtin_amdgcn_mfma_f32_16x16x32_bf16(e1f[i], w2f[j], av1[i][j], 0, 0, 0);
          }
      };

      // 4-slot ring, 3 ahead: 21 outstanding/wave; vmcnt(14) completes oldest 7.
      stg1(0, 0); stg1(32, 1); stg1(64, 2);
      for (int it = 0; it < 16; ++it) {
        if (it < 14)        asm volatile("s_waitcnt vmcnt(14)" ::: "memory");
        else if (it == 14)  asm volatile("s_waitcnt vmcnt(7)" ::: "memory");
        else                asm volatile("s_waitcnt vmcnt(0)" ::: "memory");
        __builtin_amdgcn_s_barrier();
        if (it + 3 < 16) stg1((it + 3) * 32, (it + 3) & 3);
        cmp1(it & 3);
      }

      float d0s[2][4], d1s[2][4];
#pragma unroll
      for (int i = 0; i < 2; ++i)
#pragma unroll
        for (int rr = 0; rr < 4; ++rr) { d0s[i][rr] = 0.f; d1s[i][rr] = 0.f; }

#pragma unroll
      for (int j = 0; j < 4; ++j) {
        const int gcol = col0 + wn * 64 + j * 16 + r16;
        const float colb = b1v[gcol] + tstage * tw1v[gcol];
#pragma unroll
        for (int i = 0; i < 2; ++i) {
          const int rbase = row0 + wm * 32 + i * 16 + q * 4;   // C/D: row=quad*4+reg
#pragma unroll
          for (int rr = 0; rr < 4; ++rr) {
            float hv = fast_tanh(az[i][j][rr] + colb);
            hbuf[(size_t)(rbase + rr) * H_N + gcol] = f2bf(hv);
            float sd = 1.f - hv * hv;
            d0s[i][rr] += sd * au0[i][j][rr] * av0[i][j][rr];
            d1s[i][rr] += sd * au1[i][j][rr] * av1[i][j][rr];
          }
        }
      }
#pragma unroll
      for (int i = 0; i < 2; ++i)
#pragma unroll
        for (int rr = 0; rr < 4; ++rr) {
          float a = d0s[i][rr], bb = d1s[i][rr];
#pragma unroll
          for (int m = 1; m < 16; m <<= 1) { a += __shfl_xor(a, m); bb += __shfl_xor(bb, m); }
          if (r16 == 0) {
            int grow = row0 + wm * 32 + i * 16 + q * 4 + rr;
            atomicAdd(&div0[grow], a);
            atomicAdd(&div1[grow], bb);
          }
        }
    }
    tgt += 8; slab_bar(ctr, tgt);

    // ================= f3 phase (+ lp/div apply, + egen for stage st+4) =================
    {
      const int col0 = bh * 64;
      u16* S3 = &S[0][0];                  // 4 ring slots of 4096 u16 (A 2048 | B 2048)

      f32x4 a3[2][2];
      a3[0][0] = (f32x4){0,0,0,0}; a3[0][1] = (f32x4){0,0,0,0};
      a3[1][0] = (f32x4){0,0,0,0}; a3[1][1] = (f32x4){0,0,0,0};

      const u16* gp3[2];
      gp3[0] = hbuf + (size_t)(row0 + wave * 16 + srow) * 1024 + scol;
      gp3[1] = W2T  + (size_t)(col0 + wave * 16 + srow) * 1024 + scol;

      auto stg3 = [&](int kt, int slot) {
        u16* b = S3 + slot * 4096;
        __builtin_amdgcn_global_load_lds((ga_u32*)(gp3[0] + kt),
                                         (ls_u32*)(b + wave * 512), 16, 0, 0);
        __builtin_amdgcn_global_load_lds((ga_u32*)(gp3[1] + kt),
                                         (ls_u32*)(b + 2048 + wave * 512), 16, 0, 0);
      };
      auto cmp3 = [&](int slot) {
        const u16* b = S3 + slot * 4096;
        s16x8 af[2], bf[2];
#pragma unroll
        for (int i = 0; i < 2; ++i)
          af[i] = *(const s16x8*)(b + (wm * 32 + i * 16 + r16) * 32 + cqa);
#pragma unroll
        for (int j = 0; j < 2; ++j)
          bf[j] = *(const s16x8*)(b + 2048 + (wn * 32 + j * 16 + r16) * 32 + cqa);
#pragma unroll
        for (int i = 0; i < 2; ++i)
#pragma unroll
          for (int j = 0; j < 2; ++j)
            a3[i][j] = __builtin_amdgcn_mfma_f32_16x16x32_bf16(af[i], bf[j], a3[i][j], 0, 0, 0);
      };

      // 4-slot ring, 3 ahead: 6 outstanding/wave; vmcnt(4) completes oldest 2.
      stg3(0, 0); stg3(32, 1); stg3(64, 2);
      for (int it = 0; it < 32; ++it) {
        if (it < 30)        asm volatile("s_waitcnt vmcnt(4)" ::: "memory");
        else if (it == 30)  asm volatile("s_waitcnt vmcnt(2)" ::: "memory");
        else                asm volatile("s_waitcnt vmcnt(0)" ::: "memory");
        __builtin_amdgcn_s_barrier();
        if (it + 3 < 32) stg3((it + 3) * 32, (it + 3) & 3);
        cmp3(it & 3);
      }

      if (bh == 0 && tid < 64) {           // apply clipped div to lp; reset accumulators
        int b = row0 + tid;
        float c = 0.5f * (div0[b] + div1[b]);
        c = fminf(fmaxf(c, -100.f), 100.f);
        lp[b] -= wdt * c;
        div0[b] = 0.f; div1[b] = 0.f;
      }

      // RK38 epilogue
#pragma unroll
      for (int j = 0; j < 2; ++j) {
        const int gcol = col0 + wn * 32 + j * 16 + r16;
        const float cb = b2v[gcol];
#pragma unroll
        for (int i = 0; i < 2; ++i) {
          const int rbase = row0 + wm * 32 + i * 16 + q * 4;
#pragma unroll
          for (int rr = 0; rr < 4; ++rr) {
            const size_t idx2 = (size_t)(rbase + rr) * D_N + gcol;
            const float f = a3[i][j][rr] + cb;
            if (rsub == 0) {
              ACC[idx2] = dtt * 0.125f * f;
              T[idx2]   = dtt * f;
              zin[idx2] = f2bf(z[idx2] + dtt * f * (1.f / 3.f));
            } else if (rsub == 1) {
              float t_ = T[idx2];
              ACC[idx2] += 0.375f * dtt * f;
              zin[idx2] = f2bf(z[idx2] + dtt * f - t_ * (1.f / 3.f));
              T[idx2]   = t_ - dtt * f;
            } else if (rsub == 2) {
              ACC[idx2] += 0.375f * dtt * f;
              zin[idx2] = f2bf(z[idx2] + T[idx2] + dtt * f);
            } else {
              float zn = z[idx2] + ACC[idx2] + dtt * 0.125f * f;
              z[idx2]   = zn;
              zin[idx2] = f2bf(zn);
            }
          }
        }
      }

      // regen e for stage st+4 into the slot f1(st) just freed (slab-local).
      if (st + 4 < 36) egen_unit(st + 4, bh * 256 + tid);
    }
    tgt += 8; slab_bar(ctr, tgt);
  }

  // ================= out phase: rep + logprob =================
#pragma unroll
  for (int rr = 0; rr < 2; ++rr) {
    const int b = bm * 64 + bh * 8 + wave * 2 + rr;
    const float* zr = z + (size_t)b * D_N + lane * 8;
    float4 v0 = *(const float4*)zr;
    float4 v1 = *(const float4*)(zr + 4);
    *(float4*)(outp + (size_t)b * D_N + lane * 8)     = v0;
    *(float4*)(outp + (size_t)b * D_N + lane * 8 + 4) = v1;
    float ss = v0.x*v0.x + v0.y*v0.y + v0.z*v0.z + v0.w*v0.w
             + v1.x*v1.x + v1.y*v1.y + v1.z*v1.z + v1.w*v1.w;
#pragma unroll
    for (int m = 1; m < 64; m <<= 1) ss += __shfl_xor(ss, m);
    if (lane == 0) outp[(size_t)BD + b] = -0.5f * ss + lp[b];
  }
}

extern "C" void kernel_launch(void* const* d_in, const int* in_sizes, int n_in,
                              void* d_out, int out_size, void* d_ws, size_t ws_size,
                              hipStream_t stream) {
  const float* x   = (const float*)d_in[0];
  const float* W1  = (const float*)d_in[1];
  const float* b1  = (const float*)d_in[2];
  const float* tw1 = (const float*)d_in[3];
  const float* W2  = (const float*)d_in[4];
  const float* b2  = (const float*)d_in[5];
  float* outp = (float*)d_out;

  const size_t NEEDED = (size_t)45 << 20;
  if (ws_size < NEEDED) {
    k_sentinel<<<(BD + B_N + 255) / 256, 256, 0, stream>>>(outp, BD + B_N);
    return;
  }
  char* w = (char*)d_ws;
  auto carve = [&](size_t bytes) { char* p = w; w += (bytes + 255) & ~(size_t)255; return p; };
  uint32_t* keys = (uint32_t*)carve(144 * sizeof(uint32_t));
  u16* ebf   = (u16*)carve((size_t)4 * 2 * BD * 2);               // 16 MB: 4-slot e ring
  float* z   = (float*)carve((size_t)BD * 4);
  float* ACC = (float*)carve((size_t)BD * 4);
  float* T   = (float*)carve((size_t)BD * 4);
  u16* zin   = (u16*)carve((size_t)BD * 2);
  u16* hbuf  = (u16*)carve((size_t)B_N * H_N * 2);
  u16* W1T   = (u16*)carve((size_t)H_N * D_N * 2);
  u16* W2b   = (u16*)carve((size_t)H_N * D_N * 2);
  u16* W2T   = (u16*)carve((size_t)D_N * H_N * 2);
  float* lp   = (float*)carve((size_t)B_N * 4);
  float* div0 = (float*)carve((size_t)B_N * 4);
  float* div1 = (float*)carve((size_t)B_N * 4);
  uint32_t* barv = (uint32_t*)carve(4096);       // 32 slab counters, 128B stride

  k_keysched<<<1, 1, 0, stream>>>(keys);
  k_init<<<BD / 256, 256, 0, stream>>>(x, z, zin, lp, div0, div1, barv);
  k_cvtT<<<(D_N * H_N) / 256, 256, 0, stream>>>(W1, W1T, D_N, H_N);
  k_cvt <<<(H_N * D_N) / 256, 256, 0, stream>>>(W2, W2b, H_N * D_N);
  k_cvtT<<<(H_N * D_N) / 256, 256, 0, stream>>>(W2, W2T, H_N, D_N);

  k_fused<<<256, 256, 0, stream>>>(keys, ebf, zin, W1T, W2b, W2T, b1, tw1, b2,
                                   z, ACC, T, hbuf, lp, div0, div1, barv, outp);
}

// Round 6
// 1452.117 us; speedup vs baseline: 1.9494x; 1.2908x over previous
//
#include <hip/hip_runtime.h>
#include <stdint.h>

// FFJORD block: B=2048, D=512, H=1024, 9 RK38 steps x 4 stages, 2 Hutchinson probes.
// f32 in/out. bf16 MFMA GEMMs, f32 accumulate, fp32 RK state.
// PRNG: JAX threefry partitionable (verified R7).
// R19 (resubmit; R5 bench was GPUAcquisitionTimeout — never ran):
// fence-free slab coherence. R18 attribution: FETCH 1.05GB (3-4x ideal),
// 70% stall => RELEASE(buffer_wbl2)+ACQUIRE(buffer_inv) per block per phase
// nukes the XCD L2 73x8 times. All slab traffic is same-XCD-L2: L1 is
// write-through, atomics execute at L2 => correct protocol is (a) producer
// vmcnt(0) drain before RELAXED signal, (b) consumer reads bypass stale L1
// via sc0 (global_load_lds aux=1, CPol bit0), (c) div/lp cross-block scalars
// via relaxed-agent atomic loads. Zero cache-maintenance instructions.
// Else identical to R18 (4-ring counted vmcnt, balanced egen, slab barriers).

#define B_N 2048
#define D_N 512
#define H_N 1024
#define BD (B_N * D_N)

typedef unsigned short u16;
typedef __attribute__((ext_vector_type(8))) short s16x8;   // 8 x bf16
typedef __attribute__((ext_vector_type(4))) float f32x4;   // MFMA accumulator

typedef __attribute__((address_space(1))) const uint32_t ga_u32;
typedef __attribute__((address_space(3))) uint32_t ls_u32;

#if __has_builtin(__builtin_amdgcn_alignbit)
#define ROTL32(x, r) __builtin_amdgcn_alignbit((x), (x), 32 - (r))
#else
#define ROTL32(x, r) (((x) << (r)) | ((x) >> (32 - (r))))
#endif

__device__ __forceinline__ u16 f2bf(float f) {
  union { float f; uint32_t u; } c; c.f = f;
  uint32_t r = c.u + 0x7FFFu + ((c.u >> 16) & 1u);  // RTNE
  return (u16)(r >> 16);
}
__device__ __forceinline__ float fast_tanh(float v) {
  float e = __expf(2.0f * fabsf(v));
  float t = 1.0f - 2.0f / (e + 1.0f);
  return copysignf(t, v);
}

struct U2 { uint32_t x, y; };

// Threefry-2x32, 20 rounds — KAT-verified.
__device__ __forceinline__ U2 tf2x32(uint32_t k0, uint32_t k1, uint32_t x0, uint32_t x1) {
  uint32_t k2 = k0 ^ k1 ^ 0x1BD11BDAu;
#define RND(r) { x0 += x1; x1 = ROTL32(x1, r); x1 ^= x0; }
  x0 += k0; x1 += k1;
  RND(13) RND(15) RND(26) RND(6)
  x0 += k1; x1 += k2 + 1u;
  RND(17) RND(29) RND(16) RND(24)
  x0 += k2; x1 += k0 + 2u;
  RND(13) RND(15) RND(26) RND(6)
  x0 += k0; x1 += k1 + 3u;
  RND(17) RND(29) RND(16) RND(24)
  x0 += k1; x1 += k2 + 4u;
  RND(13) RND(15) RND(26) RND(6)
  x0 += k2; x1 += k0 + 5u;
#undef RND
  U2 r; r.x = x0; r.y = x1; return r;
}

// Partitionable key schedule (verified R7).
__global__ void k_keysched(uint32_t* __restrict__ ekeys) {
  if (threadIdx.x != 0 || blockIdx.x != 0) return;
  uint32_t kx = 0u, ky = 1234u;
  for (int s = 0; s < 9; ++s) {
    for (int st = 0; st < 4; ++st) {
      U2 kst = tf2x32(kx, ky, 0u, (uint32_t)(st + 1));
      for (int pr = 0; pr < 2; ++pr) {
        U2 fo = tf2x32(kst.x, kst.y, 0u, (uint32_t)pr);
        U2 k2 = tf2x32(fo.x, fo.y, 0u, 1u);
        ekeys[(s * 4 + st) * 4 + pr * 2 + 0] = k2.x;
        ekeys[(s * 4 + st) * 4 + pr * 2 + 1] = k2.y;
      }
    }
    U2 c = tf2x32(kx, ky, 0u, 0u);
    kx = c.x; ky = c.y;
  }
}

__global__ void k_init(const float* __restrict__ x, float* __restrict__ z, u16* __restrict__ zin,
                       float* __restrict__ lp, float* __restrict__ d0, float* __restrict__ d1,
                       uint32_t* __restrict__ barv) {
  int i = blockIdx.x * 256 + threadIdx.x;
  if (i < BD) { float v = x[i]; z[i] = v; zin[i] = f2bf(v); }
  if (i < B_N) { lp[i] = 0.f; d0[i] = 0.f; d1[i] = 0.f; }
  if (i < 1024) barv[i] = 0u;                    // 32 slab counters, 128B stride
}

__global__ void k_cvtT(const float* __restrict__ src, u16* __restrict__ dst, int R, int C) {
  int i = blockIdx.x * 256 + threadIdx.x;
  if (i >= R * C) return;
  int c = i / R, r = i - c * R;
  dst[i] = f2bf(src[(size_t)r * C + c]);
}
__global__ void k_cvt(const float* __restrict__ src, u16* __restrict__ dst, int n) {
  int i = blockIdx.x * 256 + threadIdx.x;
  if (i < n) dst[i] = f2bf(src[i]);
}

__global__ void k_sentinel(float* __restrict__ out, int n) {
  int i = blockIdx.x * 256 + threadIdx.x;
  if (i < n) out[i] = 12345.0f;
}

// 8-way slab barrier, fence-free (monotonic counter, re-zeroed each replay).
// All 8 participants share one XCD L2 (the coherence point): L1 is
// write-through so stores reach L2 at vmcnt retirement; consumers bypass
// stale L1 via sc0 loads. Protocol: drain vmcnt -> RELAXED RMW -> RELAXED
// poll -> s_barrier. No buffer_wbl2 / buffer_inv.
__device__ __forceinline__ void slab_bar(uint32_t* ctr, uint32_t tgt) {
  asm volatile("s_waitcnt vmcnt(0)" ::: "memory");
  __syncthreads();
  if (threadIdx.x == 0) {
    __hip_atomic_fetch_add(ctr, 1u, __ATOMIC_RELAXED, __HIP_MEMORY_SCOPE_AGENT);
    while (__hip_atomic_load(ctr, __ATOMIC_RELAXED, __HIP_MEMORY_SCOPE_AGENT) < tgt)
      __builtin_amdgcn_s_sleep(1);
  }
  __syncthreads();
}

// LDS chunk swizzle (R13-verified): chunk c of 16-row-group row r at chunk c^((r>>1)&3).
// f1: 64x128 block tile, 4 waves of 32x64, K=512, 16 K-steps, 4-ring vmcnt(14).
// f3: 64x64 block tile, 4 waves of 32x32, K=1024, 32 K-steps, 4-ring vmcnt(4).
__global__ __launch_bounds__(256, 1)
void k_fused(const uint32_t* __restrict__ keys, u16* __restrict__ ebf,
             u16* __restrict__ zin,
             const u16* __restrict__ W1T, const u16* __restrict__ W2b, const u16* __restrict__ W2T,
             const float* __restrict__ b1v, const float* __restrict__ tw1v, const float* __restrict__ b2v,
             float* __restrict__ z, float* __restrict__ ACC, float* __restrict__ T,
             u16* __restrict__ hbuf,
             float* __restrict__ lp, float* __restrict__ div0, float* __restrict__ div1,
             uint32_t* __restrict__ barv, float* __restrict__ outp) {
  __shared__ u16 S[4][14336];   // 112KB: f1 ring [zin|e0|e1|W1|W2]x4; f3 ring aliased at base
  const int tid = threadIdx.x, wave = tid >> 6, lane = tid & 63;
  const int xcd = blockIdx.x & 7, idx = blockIdx.x >> 3;   // 256 blocks: 32/XCD
  const int bm = xcd * 4 + (idx >> 3);       // row-slab of 64, pinned to XCD
  const int bh = idx & 7;                    // f1: col-block of 128; f3: col-block of 64
  const int row0 = bm * 64;
  const int wm = wave >> 1, wn = wave & 1, r16 = lane & 15, q = lane >> 4;
  const int srow = lane >> 2;
  const int scol = (((lane & 3) ^ ((srow >> 1) & 3))) * 8;   // swizzled source chunk
  const int cqa = (q ^ ((r16 >> 1) & 3)) * 8;                // swizzled read chunk

  uint32_t* ctr = barv + bm * 32;            // this slab's barrier counter
  uint32_t tgt = 0;

  // ---- egen: one (stage, unit) task per call; slab-local ----
  auto egen_unit = [&](int stg, int u) {
    const int probe = u >> 10, unit = u & 1023;
    const uint32_t p0 = (uint32_t)(bm * 32768 + unit * 32);
    uint32_t k0 = keys[stg * 4 + probe * 2], k1 = keys[stg * 4 + probe * 2 + 1];
    uint4* dst = (uint4*)(ebf + (size_t)(stg & 3) * (2 * (size_t)BD) + (size_t)probe * BD + (size_t)p0);
#pragma unroll
    for (int g = 0; g < 4; ++g) {
      uint32_t pr[4];
#pragma unroll
      for (int h = 0; h < 4; ++h) {
        uint32_t c0 = p0 + g * 8 + h * 2;
        U2 r0 = tf2x32(k0, k1, 0u, c0);
        U2 r1 = tf2x32(k0, k1, 0u, c0 + 1u);
        pr[h] = (((r0.x ^ r0.y) & 1u) ? 0x3F80u : 0xBF80u) |
                (((r1.x ^ r1.y) & 1u) ? 0x3F800000u : 0xBF800000u);
      }
      uint4 v; v.x = pr[0]; v.y = pr[1]; v.z = pr[2]; v.w = pr[3];
      dst[g] = v;
    }
  };

  // Prologue: e for stages 0..3 of this slab (2048 threads x 4 tasks).
#pragma unroll
  for (int r = 0; r < 4; ++r) egen_unit(r, bh * 256 + tid);
  tgt += 8; slab_bar(ctr, tgt);

  for (int st = 0; st < 36; ++st) {
    const int s9 = st >> 2, rsub = st & 3;
    const float t0f = (float)s9 / 9.0f;
    const float t1f = (float)(s9 + 1) / 9.0f;
    const float dtt = t1f - t0f;
    const float tstage = (rsub == 0) ? t0f : (rsub == 1) ? (t0f + dtt / 3.0f)
                       : (rsub == 2) ? (t0f + dtt * 2.0f / 3.0f) : t1f;
    const float wdt = dtt * 0.125f * ((rsub == 1 || rsub == 2) ? 3.0f : 1.0f);

    // ================= f1 phase =================
    {
      const u16* e0g = ebf + (size_t)(st & 3) * (2 * (size_t)BD);
      const u16* e1g = e0g + BD;
      const int col0 = bh * 128;

      f32x4 az[2][4], au0[2][4], au1[2][4], av0[2][4], av1[2][4];
#pragma unroll
      for (int i = 0; i < 2; ++i)
#pragma unroll
        for (int j = 0; j < 4; ++j) {
          az[i][j] = (f32x4){0,0,0,0}; au0[i][j] = (f32x4){0,0,0,0}; au1[i][j] = (f32x4){0,0,0,0};
          av0[i][j] = (f32x4){0,0,0,0}; av1[i][j] = (f32x4){0,0,0,0};
        }

      // slot s = li*4+wave: s<12 -> A {zin,e0,e1} part s&3; s>=12 -> B {W1T,W2b} part (s-12)&7
      const u16* gp[7];
#pragma unroll
      for (int li = 0; li < 7; ++li) {
        const int s = li * 4 + wave;
        const u16* base;
        int row;
        if (s < 12) {
          const int mat = s >> 2;
          base = (mat == 0) ? zin : (mat == 1) ? e0g : e1g;
          row = row0 + (s & 3) * 16 + srow;
        } else {
          const int t = s - 12;
          base = (t < 8) ? W1T : W2b;
          row = col0 + (t & 7) * 16 + srow;
        }
        gp[li] = base + (size_t)row * 512 + scol;
      }

      auto stg1 = [&](int kt, int slot) {
        u16* b = &S[slot][0];
#pragma unroll
        for (int li = 0; li < 7; ++li)
          __builtin_amdgcn_global_load_lds((ga_u32*)(gp[li] + kt),
                                           (ls_u32*)(b + (li * 4 + wave) * 512), 16, 0, 1); // sc0
      };
      auto cmp1 = [&](int slot) {
        const u16* b = &S[slot][0];
        s16x8 zf[2], e0f[2], e1f[2], w1f[4], w2f[4];
#pragma unroll
        for (int i = 0; i < 2; ++i) {
          const int ao = (wm * 32 + i * 16 + r16) * 32 + cqa;
          zf[i]  = *(const s16x8*)(b + 0    + ao);
          e0f[i] = *(const s16x8*)(b + 2048 + ao);
          e1f[i] = *(const s16x8*)(b + 4096 + ao);
        }
#pragma unroll
        for (int j = 0; j < 4; ++j) {
          const int bo = (wn * 64 + j * 16 + r16) * 32 + cqa;
          w1f[j] = *(const s16x8*)(b + 6144  + bo);
          w2f[j] = *(const s16x8*)(b + 10240 + bo);
        }
#pragma unroll
        for (int i = 0; i < 2; ++i)
#pragma unroll
          for (int j = 0; j < 4; ++j) {
            az[i][j]  = __builtin_amdgcn_mfma_f32_16x16x32_bf16(zf[i],  w1f[j], az[i][j],  0, 0, 0);
            au0[i][j] = __builtin_amdgcn_mfma_f32_16x16x32_bf16(e0f[i], w1f[j], au0[i][j], 0, 0, 0);
            au1[i][j] = __builtin_amdgcn_mfma_f32_16x16x32_bf16(e1f[i], w1f[j], au1[i][j], 0, 0, 0);
            av0[i][j] = __builtin_amdgcn_mfma_f32_16x16x32_bf16(e0f[i], w2f[j], av0[i][j], 0, 0, 0);
            av1[i][j] = __builtin_amdgcn_mfma_f32_16x16x32_bf16(e1f[i], w2f[j], av1[i][j], 0, 0, 0);
          }
      };

      // 4-slot ring, 3 ahead: 21 outstanding/wave; vmcnt(14) completes oldest 7.
      stg1(0, 0); stg1(32, 1); stg1(64, 2);
      for (int it = 0; it < 16; ++it) {
        if (it < 14)        asm volatile("s_waitcnt vmcnt(14)" ::: "memory");
        else if (it == 14)  asm volatile("s_waitcnt vmcnt(7)" ::: "memory");
        else                asm volatile("s_waitcnt vmcnt(0)" ::: "memory");
        __builtin_amdgcn_s_barrier();
        if (it + 3 < 16) stg1((it + 3) * 32, (it + 3) & 3);
        cmp1(it & 3);
      }

      float d0s[2][4], d1s[2][4];
#pragma unroll
      for (int i = 0; i < 2; ++i)
#pragma unroll
        for (int rr = 0; rr < 4; ++rr) { d0s[i][rr] = 0.f; d1s[i][rr] = 0.f; }

#pragma unroll
      for (int j = 0; j < 4; ++j) {
        const int gcol = col0 + wn * 64 + j * 16 + r16;
        const float colb = b1v[gcol] + tstage * tw1v[gcol];
#pragma unroll
        for (int i = 0; i < 2; ++i) {
          const int rbase = row0 + wm * 32 + i * 16 + q * 4;   // C/D: row=quad*4+reg
#pragma unroll
          for (int rr = 0; rr < 4; ++rr) {
            float hv = fast_tanh(az[i][j][rr] + colb);
            hbuf[(size_t)(rbase + rr) * H_N + gcol] = f2bf(hv);
            float sd = 1.f - hv * hv;
            d0s[i][rr] += sd * au0[i][j][rr] * av0[i][j][rr];
            d1s[i][rr] += sd * au1[i][j][rr] * av1[i][j][rr];
          }
        }
      }
#pragma unroll
      for (int i = 0; i < 2; ++i)
#pragma unroll
        for (int rr = 0; rr < 4; ++rr) {
          float a = d0s[i][rr], bb = d1s[i][rr];
#pragma unroll
          for (int m = 1; m < 16; m <<= 1) { a += __shfl_xor(a, m); bb += __shfl_xor(bb, m); }
          if (r16 == 0) {
            int grow = row0 + wm * 32 + i * 16 + q * 4 + rr;
            atomicAdd(&div0[grow], a);
            atomicAdd(&div1[grow], bb);
          }
        }
    }
    tgt += 8; slab_bar(ctr, tgt);

    // ================= f3 phase (+ lp/div apply, + egen for stage st+4) =================
    {
      const int col0 = bh * 64;
      u16* S3 = &S[0][0];                  // 4 ring slots of 4096 u16 (A 2048 | B 2048)

      f32x4 a3[2][2];
      a3[0][0] = (f32x4){0,0,0,0}; a3[0][1] = (f32x4){0,0,0,0};
      a3[1][0] = (f32x4){0,0,0,0}; a3[1][1] = (f32x4){0,0,0,0};

      const u16* gp3[2];
      gp3[0] = hbuf + (size_t)(row0 + wave * 16 + srow) * 1024 + scol;
      gp3[1] = W2T  + (size_t)(col0 + wave * 16 + srow) * 1024 + scol;

      auto stg3 = [&](int kt, int slot) {
        u16* b = S3 + slot * 4096;
        __builtin_amdgcn_global_load_lds((ga_u32*)(gp3[0] + kt),
                                         (ls_u32*)(b + wave * 512), 16, 0, 1);            // sc0
        __builtin_amdgcn_global_load_lds((ga_u32*)(gp3[1] + kt),
                                         (ls_u32*)(b + 2048 + wave * 512), 16, 0, 1);     // sc0
      };
      auto cmp3 = [&](int slot) {
        const u16* b = S3 + slot * 4096;
        s16x8 af[2], bf[2];
#pragma unroll
        for (int i = 0; i < 2; ++i)
          af[i] = *(const s16x8*)(b + (wm * 32 + i * 16 + r16) * 32 + cqa);
#pragma unroll
        for (int j = 0; j < 2; ++j)
          bf[j] = *(const s16x8*)(b + 2048 + (wn * 32 + j * 16 + r16) * 32 + cqa);
#pragma unroll
        for (int i = 0; i < 2; ++i)
#pragma unroll
          for (int j = 0; j < 2; ++j)
            a3[i][j] = __builtin_amdgcn_mfma_f32_16x16x32_bf16(af[i], bf[j], a3[i][j], 0, 0, 0);
      };

      // 4-slot ring, 3 ahead: 6 outstanding/wave; vmcnt(4) completes oldest 2.
      stg3(0, 0); stg3(32, 1); stg3(64, 2);
      for (int it = 0; it < 32; ++it) {
        if (it < 30)        asm volatile("s_waitcnt vmcnt(4)" ::: "memory");
        else if (it == 30)  asm volatile("s_waitcnt vmcnt(2)" ::: "memory");
        else                asm volatile("s_waitcnt vmcnt(0)" ::: "memory");
        __builtin_amdgcn_s_barrier();
        if (it + 3 < 32) stg3((it + 3) * 32, (it + 3) & 3);
        cmp3(it & 3);
      }

      if (bh == 0 && tid < 64) {           // apply clipped div to lp; reset accumulators
        int b = row0 + tid;
        float c0 = __hip_atomic_load(&div0[b], __ATOMIC_RELAXED, __HIP_MEMORY_SCOPE_AGENT);
        float c1 = __hip_atomic_load(&div1[b], __ATOMIC_RELAXED, __HIP_MEMORY_SCOPE_AGENT);
        float c = 0.5f * (c0 + c1);
        c = fminf(fmaxf(c, -100.f), 100.f);
        lp[b] -= wdt * c;
        div0[b] = 0.f; div1[b] = 0.f;
      }

      // RK38 epilogue
#pragma unroll
      for (int j = 0; j < 2; ++j) {
        const int gcol = col0 + wn * 32 + j * 16 + r16;
        const float cb = b2v[gcol];
#pragma unroll
        for (int i = 0; i < 2; ++i) {
          const int rbase = row0 + wm * 32 + i * 16 + q * 4;
#pragma unroll
          for (int rr = 0; rr < 4; ++rr) {
            const size_t idx2 = (size_t)(rbase + rr) * D_N + gcol;
            const float f = a3[i][j][rr] + cb;
            if (rsub == 0) {
              ACC[idx2] = dtt * 0.125f * f;
              T[idx2]   = dtt * f;
              zin[idx2] = f2bf(z[idx2] + dtt * f * (1.f / 3.f));
            } else if (rsub == 1) {
              float t_ = T[idx2];
              ACC[idx2] += 0.375f * dtt * f;
              zin[idx2] = f2bf(z[idx2] + dtt * f - t_ * (1.f / 3.f));
              T[idx2]   = t_ - dtt * f;
            } else if (rsub == 2) {
              ACC[idx2] += 0.375f * dtt * f;
              zin[idx2] = f2bf(z[idx2] + T[idx2] + dtt * f);
            } else {
              float zn = z[idx2] + ACC[idx2] + dtt * 0.125f * f;
              z[idx2]   = zn;
              zin[idx2] = f2bf(zn);
            }
          }
        }
      }

      // regen e for stage st+4 into the slot f1(st) just freed (slab-local).
      if (st + 4 < 36) egen_unit(st + 4, bh * 256 + tid);
    }
    tgt += 8; slab_bar(ctr, tgt);
  }

  // ================= out phase: rep + logprob =================
#pragma unroll
  for (int rr = 0; rr < 2; ++rr) {
    const int b = bm * 64 + bh * 8 + wave * 2 + rr;
    const float* zr = z + (size_t)b * D_N + lane * 8;
    float4 v0 = *(const float4*)zr;
    float4 v1 = *(const float4*)(zr + 4);
    *(float4*)(outp + (size_t)b * D_N + lane * 8)     = v0;
    *(float4*)(outp + (size_t)b * D_N + lane * 8 + 4) = v1;
    float ss = v0.x*v0.x + v0.y*v0.y + v0.z*v0.z + v0.w*v0.w
             + v1.x*v1.x + v1.y*v1.y + v1.z*v1.z + v1.w*v1.w;
#pragma unroll
    for (int m = 1; m < 64; m <<= 1) ss += __shfl_xor(ss, m);
    if (lane == 0) {
      float lpv = __hip_atomic_load(&lp[b], __ATOMIC_RELAXED, __HIP_MEMORY_SCOPE_AGENT);
      outp[(size_t)BD + b] = -0.5f * ss + lpv;
    }
  }
}

extern "C" void kernel_launch(void* const* d_in, const int* in_sizes, int n_in,
                              void* d_out, int out_size, void* d_ws, size_t ws_size,
                              hipStream_t stream) {
  const float* x   = (const float*)d_in[0];
  const float* W1  = (const float*)d_in[1];
  const float* b1  = (const float*)d_in[2];
  const float* tw1 = (const float*)d_in[3];
  const float* W2  = (const float*)d_in[4];
  const float* b2  = (const float*)d_in[5];
  float* outp = (float*)d_out;

  const size_t NEEDED = (size_t)45 << 20;
  if (ws_size < NEEDED) {
    k_sentinel<<<(BD + B_N + 255) / 256, 256, 0, stream>>>(outp, BD + B_N);
    return;
  }
  char* w = (char*)d_ws;
  auto carve = [&](size_t bytes) { char* p = w; w += (bytes + 255) & ~(size_t)255; return p; };
  uint32_t* keys = (uint32_t*)carve(144 * sizeof(uint32_t));
  u16* ebf   = (u16*)carve((size_t)4 * 2 * BD * 2);               // 16 MB: 4-slot e ring
  float* z   = (float*)carve((size_t)BD * 4);
  float* ACC = (float*)carve((size_t)BD * 4);
  float* T   = (float*)carve((size_t)BD * 4);
  u16* zin   = (u16*)carve((size_t)BD * 2);
  u16* hbuf  = (u16*)carve((size_t)B_N * H_N * 2);
  u16* W1T   = (u16*)carve((size_t)H_N * D_N * 2);
  u16* W2b   = (u16*)carve((size_t)H_N * D_N * 2);
  u16* W2T   = (u16*)carve((size_t)D_N * H_N * 2);
  float* lp   = (float*)carve((size_t)B_N * 4);
  float* div0 = (float*)carve((size_t)B_N * 4);
  float* div1 = (float*)carve((size_t)B_N * 4);
  uint32_t* barv = (uint32_t*)carve(4096);       // 32 slab counters, 128B stride

  k_keysched<<<1, 1, 0, stream>>>(keys);
  k_init<<<BD / 256, 256, 0, stream>>>(x, z, zin, lp, div0, div1, barv);
  k_cvtT<<<(D_N * H_N) / 256, 256, 0, stream>>>(W1, W1T, D_N, H_N);
  k_cvt <<<(H_N * D_N) / 256, 256, 0, stream>>>(W2, W2b, H_N * D_N);
  k_cvtT<<<(H_N * D_N) / 256, 256, 0, stream>>>(W2, W2T, H_N, D_N);

  k_fused<<<256, 256, 0, stream>>>(keys, ebf, zin, W1T, W2b, W2T, b1, tw1, b2,
                                   z, ACC, T, hbuf, lp, div0, div1, barv, outp);
}